// Round 7
// baseline (1937.435 us; speedup 1.0000x reference)
//
#include <hip/hip_runtime.h>
#include <hip/hip_bf16.h>
#include <math.h>

namespace {
constexpr int KNB  = 7;                  // neighbor volumes
constexpr int PS   = 7;                  // patch size
constexpr int CCH  = 3;                  // image channels
constexpr int IH   = 256;
constexpr int IW   = 256;
constexpr int PADR = 3;                  // PS/2
constexpr int QN   = IH * IW;            // 65536
constexpr int ON   = 32;                 // candidates per query
constexpr int EN   = 64;                 // embedding dim
constexpr int FN   = CCH * PS * PS;      // 147
constexpr int KC   = KNB * CCH;          // 21 output channels per map
constexpr int TQY  = 8;                  // tile rows
constexpr int TQX  = 4;                  // tile cols (= waves per block)
constexpr int CHY  = TQY + PS - 1;       // 14
constexpr int CHX  = TQX + PS - 1;       // 10
constexpr int CELEM = KC * CHY * CHX;    // 2940 canvas floats
constexpr int NW   = 4;                  // waves per block
constexpr int NBX  = IW / TQX;           // 64
constexpr int NBY  = IH / TQY;           // 32
}

__device__ __forceinline__ float bf16_to_f(unsigned short u) {
    union { unsigned int i; float f; } c;
    c.i = ((unsigned int)u) << 16;
    return c.f;
}

// x fp32 -> bf16 (RNE), vectorized 4-wide. Packed [N][147] rows.
__global__ __launch_bounds__(256) void conv_kernel(
    const float* __restrict__ x, unsigned short* __restrict__ xb, int n4)
{
    int i = blockIdx.x * blockDim.x + threadIdx.x;
    if (i >= n4) return;
    float4 v = ((const float4*)x)[i];
    ushort4 o;
    o.x = __hip_bfloat16_raw(__float2bfloat16(v.x)).x;
    o.y = __hip_bfloat16_raw(__float2bfloat16(v.y)).x;
    o.z = __hip_bfloat16_raw(__float2bfloat16(v.z)).x;
    o.w = __hip_bfloat16_raw(__float2bfloat16(v.w)).x;
    ((ushort4*)xb)[i] = o;
}

// One block = 8x4 query tile, 4 waves (256 thr); wave = one tile column,
// 8 queries serially. Fold accumulates into an LDS canvas; one atomic
// flush per block. The wpsum gather is register-batched: 24 independent
// bf16 loads issued per 8-row batch BEFORE any use -> high MLP per wave.
// NOTE: never cap VGPR below natural: caps of 32 spilled ~1GB scratch in
// rounds 3&4. (256,4) caps at 128.
__global__ __launch_bounds__(256, 4) void n3_tile_kernel(
    const unsigned short* __restrict__ xb,  // [N][147] bf16
    const float* __restrict__ xe,           // [N, E]
    const float* __restrict__ ye,           // [Q, E]
    const float* __restrict__ log_temp,     // [H, W]
    const int*   __restrict__ cand,         // [Q, O]
    const int*   __restrict__ qindex,       // [Q]
    float*       __restrict__ vid)          // [KC, H, W] (pre-zeroed)
{
    __shared__ float canvas[CELEM];     // [KC][CHY][CHX]
    __shared__ float w_lds[NW][ON][8];  // per-wave weights, padded row
    __shared__ int   off_lds[NW][ON];   // per-wave candidate row offsets (elems)

    const int wib  = threadIdx.x >> 6;  // 0..3 = tile column
    const int lane = threadIdx.x & 63;
    const int by   = blockIdx.x / NBX;
    const int bx   = blockIdx.x - by * NBX;
    const int y0   = by * TQY;
    const int x0   = bx * TQX;

    for (int i = threadIdx.x; i < CELEM; i += 256) canvas[i] = 0.f;
    __syncthreads();

    for (int ty = 0; ty < TQY; ++ty) {
        const int q = (y0 + ty) * IW + (x0 + wib);

        const int qpix = qindex[q];
        const int qi = qpix / IW;
        const int qj = qpix - qi * IW;

        // ---- lt: mean over zero-padded 7x7 log_temp patch ----
        float ltv = 0.f;
        if (lane < PS * PS) {
            int pi = lane / PS, pj = lane % PS;
            int yy = qi + pi - PADR, xx = qj + pj - PADR;
            if (yy >= 0 && yy < IH && xx >= 0 && xx < IW)
                ltv = log_temp[yy * IW + xx];
        }
        #pragma unroll
        for (int s = 32; s >= 1; s >>= 1) ltv += __shfl_xor(ltv, s);
        const float itemp = expf(-ltv * (1.f / 49.f));   // 1/exp(lt)

        // ---- search: lane = o + 32*h; each half-wave does half of E ----
        const int o = lane & 31;
        const int h = lane >> 5;
        const int cidx = cand[q * ON + o];
        if (lane < ON) off_lds[wib][o] = cidx * FN;
        {
            const float4* xr = (const float4*)(xe + (size_t)cidx * EN) + h * 8;
            const float4* yr = (const float4*)(ye + (size_t)q * EN) + h * 8;
            float dot = 0.f, xn = 0.f, yn = 0.f;
            #pragma unroll
            for (int e = 0; e < 8; ++e) {
                float4 a = xr[e];
                float4 b = yr[e];
                dot += a.x * b.x + a.y * b.y + a.z * b.z + a.w * b.w;
                xn  += a.x * a.x + a.y * a.y + a.z * a.z + a.w * a.w;
                yn  += b.x * b.x + b.y * b.y + b.z * b.z + b.w * b.w;
            }
            float part = xn + yn - 2.f * dot;
            part += __shfl_xor(part, 32);    // both halves hold full d2
            // ---- NNN weights: 7 iterated softmaxes over 32-lane groups ----
            float logit = -part * itemp;
            float wk[KNB];
            #pragma unroll
            for (int k = 0; k < KNB; ++k) {
                float m = logit;
                #pragma unroll
                for (int s = 16; s >= 1; s >>= 1) m = fmaxf(m, __shfl_xor(m, s));
                float ev = expf(logit - m);
                float ssum = ev;
                #pragma unroll
                for (int s = 16; s >= 1; s >>= 1) ssum += __shfl_xor(ssum, s);
                float w = ev / ssum;
                wk[k] = w;
                logit += logf(fmaxf(1.f - w, 1e-6f));
            }
            if (lane < ON) {
                #pragma unroll
                for (int k = 0; k < KNB; ++k) w_lds[wib][lane][k] = wk[k];
            }
        }
        // wave-private LDS buffers: no __syncthreads needed

        // ---- wpsum: 4 batches of 8 rows; 24 loads batched before use ----
        float acc[3][KNB];
        #pragma unroll
        for (int it = 0; it < 3; ++it)
            #pragma unroll
            for (int k = 0; k < KNB; ++k) acc[it][k] = 0.f;

        #pragma unroll
        for (int b = 0; b < 4; ++b) {
            float xv0[8], xv1[8], xv2[8];
            #pragma unroll
            for (int r = 0; r < 8; ++r) {
                const int off = off_lds[wib][b * 8 + r];
                const unsigned short* rowp = xb + off;
                xv0[r] = bf16_to_f(rowp[lane]);
                xv1[r] = bf16_to_f(rowp[64 + lane]);
                xv2[r] = (lane < FN - 128) ? bf16_to_f(rowp[128 + lane]) : 0.f;
            }
            #pragma unroll
            for (int r = 0; r < 8; ++r) {
                const int oo = b * 8 + r;
                const float4 wa = *(const float4*)&w_lds[wib][oo][0];
                const float4 wb = *(const float4*)&w_lds[wib][oo][4];
                acc[0][0] += xv0[r] * wa.x;  acc[1][0] += xv1[r] * wa.x;  acc[2][0] += xv2[r] * wa.x;
                acc[0][1] += xv0[r] * wa.y;  acc[1][1] += xv1[r] * wa.y;  acc[2][1] += xv2[r] * wa.y;
                acc[0][2] += xv0[r] * wa.z;  acc[1][2] += xv1[r] * wa.z;  acc[2][2] += xv2[r] * wa.z;
                acc[0][3] += xv0[r] * wa.w;  acc[1][3] += xv1[r] * wa.w;  acc[2][3] += xv2[r] * wa.w;
                acc[0][4] += xv0[r] * wb.x;  acc[1][4] += xv1[r] * wb.x;  acc[2][4] += xv2[r] * wb.x;
                acc[0][5] += xv0[r] * wb.y;  acc[1][5] += xv1[r] * wb.y;  acc[2][5] += xv2[r] * wb.y;
                acc[0][6] += xv0[r] * wb.z;  acc[1][6] += xv1[r] * wb.z;  acc[2][6] += xv2[r] * wb.z;
            }
        }

        // ---- fold into LDS canvas ----
        #pragma unroll
        for (int it = 0; it < 3; ++it) {
            const int f = it * 64 + lane;
            if (f < FN) {
                const int c  = f / (PS * PS);
                const int r  = f - c * (PS * PS);
                const int pi = r / PS;
                const int pj = r - pi * PS;
                const int ly = qi + pi - y0;
                const int lx = qj + pj - x0;
                #pragma unroll
                for (int k = 0; k < KNB; ++k)
                    atomicAdd(&canvas[(k * CCH + c) * (CHY * CHX) + ly * CHX + lx],
                              acc[it][k]);
            }
        }
    }

    __syncthreads();

    // ---- flush canvas to global with crop bounds-check ----
    for (int i = threadIdx.x; i < CELEM; i += 256) {
        const float v = canvas[i];
        if (v != 0.f) {
            const int ch  = i / (CHY * CHX);
            const int rem = i - ch * (CHY * CHX);
            const int ly  = rem / CHX;
            const int lx  = rem - ly * CHX;
            const int gy  = y0 - PADR + ly;
            const int gx  = x0 - PADR + lx;
            if (gy >= 0 && gy < IH && gx >= 0 && gx < IW)
                atomicAdd(&vid[(size_t)ch * QN + gy * IW + gx], v);
        }
    }
}

// Fallback (ws too small): round-2-verified structure, fp32 x gather.
__global__ __launch_bounds__(256, 4) void n3_fallback_kernel(
    const float* __restrict__ x,
    const float* __restrict__ xe,
    const float* __restrict__ ye,
    const float* __restrict__ log_temp,
    const int*   __restrict__ cand,
    const int*   __restrict__ qindex,
    float*       __restrict__ vid)
{
    __shared__ float canvas[CELEM];
    __shared__ float w_lds[NW][ON][8];
    __shared__ int   off_lds[NW][ON];

    const int wib  = threadIdx.x >> 6;
    const int lane = threadIdx.x & 63;
    const int by   = blockIdx.x / NBX;
    const int bx   = blockIdx.x - by * NBX;
    const int y0   = by * TQY;
    const int x0   = bx * TQX;

    for (int i = threadIdx.x; i < CELEM; i += 256) canvas[i] = 0.f;
    __syncthreads();

    for (int ty = 0; ty < TQY; ++ty) {
        const int q = (y0 + ty) * IW + (x0 + wib);
        const int qpix = qindex[q];
        const int qi = qpix / IW;
        const int qj = qpix - qi * IW;

        float ltv = 0.f;
        if (lane < PS * PS) {
            int pi = lane / PS, pj = lane % PS;
            int yy = qi + pi - PADR, xx = qj + pj - PADR;
            if (yy >= 0 && yy < IH && xx >= 0 && xx < IW)
                ltv = log_temp[yy * IW + xx];
        }
        #pragma unroll
        for (int s = 32; s >= 1; s >>= 1) ltv += __shfl_xor(ltv, s);
        const float itemp = expf(-ltv * (1.f / 49.f));

        const int o = lane & 31;
        const int h = lane >> 5;
        const int cidx = cand[q * ON + o];
        if (lane < ON) off_lds[wib][o] = cidx * FN;
        {
            const float4* xr = (const float4*)(xe + (size_t)cidx * EN) + h * 8;
            const float4* yr = (const float4*)(ye + (size_t)q * EN) + h * 8;
            float dot = 0.f, xn = 0.f, yn = 0.f;
            #pragma unroll
            for (int e = 0; e < 8; ++e) {
                float4 a = xr[e];
                float4 b = yr[e];
                dot += a.x * b.x + a.y * b.y + a.z * b.z + a.w * b.w;
                xn  += a.x * a.x + a.y * a.y + a.z * a.z + a.w * a.w;
                yn  += b.x * b.x + b.y * b.y + b.z * b.z + b.w * b.w;
            }
            float part = xn + yn - 2.f * dot;
            part += __shfl_xor(part, 32);
            float logit = -part * itemp;
            float wk[KNB];
            #pragma unroll
            for (int k = 0; k < KNB; ++k) {
                float m = logit;
                #pragma unroll
                for (int s = 16; s >= 1; s >>= 1) m = fmaxf(m, __shfl_xor(m, s));
                float ev = expf(logit - m);
                float ssum = ev;
                #pragma unroll
                for (int s = 16; s >= 1; s >>= 1) ssum += __shfl_xor(ssum, s);
                float w = ev / ssum;
                wk[k] = w;
                logit += logf(fmaxf(1.f - w, 1e-6f));
            }
            if (lane < ON) {
                #pragma unroll
                for (int k = 0; k < KNB; ++k) w_lds[wib][lane][k] = wk[k];
            }
        }

        #pragma unroll
        for (int it = 0; it < 3; ++it) {
            const int f = it * 64 + lane;
            const bool act = f < FN;
            float acc[KNB];
            #pragma unroll
            for (int k = 0; k < KNB; ++k) acc[k] = 0.f;
            #pragma unroll 8
            for (int oo = 0; oo < ON; ++oo) {
                const int off = off_lds[wib][oo];
                const float xv = act ? x[off + f] : 0.f;
                #pragma unroll
                for (int k = 0; k < KNB; ++k) acc[k] += xv * w_lds[wib][oo][k];
            }
            if (act) {
                const int c  = f / (PS * PS);
                const int r  = f - c * (PS * PS);
                const int pi = r / PS;
                const int pj = r - pi * PS;
                const int ly = qi + pi - y0;
                const int lx = qj + pj - x0;
                #pragma unroll
                for (int k = 0; k < KNB; ++k)
                    atomicAdd(&canvas[(k * CCH + c) * (CHY * CHX) + ly * CHX + lx], acc[k]);
            }
        }
    }

    __syncthreads();

    for (int i = threadIdx.x; i < CELEM; i += 256) {
        const float v = canvas[i];
        if (v != 0.f) {
            const int ch  = i / (CHY * CHX);
            const int rem = i - ch * (CHY * CHX);
            const int ly  = rem / CHX;
            const int lx  = rem - ly * CHX;
            const int gy  = y0 - PADR + ly;
            const int gx  = x0 - PADR + lx;
            if (gy >= 0 && gy < IH && gx >= 0 && gx < IW)
                atomicAdd(&vid[(size_t)ch * QN + gy * IW + gx], v);
        }
    }
}

// wvid = fold(ones) with qindex = arange(H*W): separable border counts.
__global__ __launch_bounds__(256) void wvid_kernel(float* __restrict__ wvid) {
    int idx = blockIdx.x * blockDim.x + threadIdx.x;
    if (idx >= QN) return;
    int y  = idx / IW;
    int xx = idx - y * IW;
    int cy = min(PS - 1, y  + PADR) - max(0, y  - (IH - 1 - PADR)) + 1;
    int cx = min(PS - 1, xx + PADR) - max(0, xx - (IW - 1 - PADR)) + 1;
    float v = (float)(cy * cx);
    #pragma unroll
    for (int ch = 0; ch < KC; ++ch) wvid[(size_t)ch * QN + idx] = v;
}

extern "C" void kernel_launch(void* const* d_in, const int* in_sizes, int n_in,
                              void* d_out, int out_size, void* d_ws, size_t ws_size,
                              hipStream_t stream) {
    const float* x    = (const float*)d_in[0];
    const float* xe   = (const float*)d_in[1];
    const float* ye   = (const float*)d_in[2];
    const float* ltm  = (const float*)d_in[3];
    const int*   cand = (const int*)d_in[4];
    const int*   qidx = (const int*)d_in[5];

    float* vid  = (float*)d_out;
    float* wvid = vid + (size_t)KC * QN;

    // vid is accumulated with atomics -> must be zeroed every launch
    hipMemsetAsync(vid, 0, (size_t)KC * QN * sizeof(float), stream);

    const size_t xelems = (size_t)QN * FN;            // 9,633,792
    const size_t xbytes = xelems * sizeof(unsigned short);

    if (ws_size >= xbytes) {
        unsigned short* xb = (unsigned short*)d_ws;
        const int n4 = (int)(xelems / 4);
        conv_kernel<<<(n4 + 255) / 256, 256, 0, stream>>>(x, xb, n4);
        n3_tile_kernel<<<NBX * NBY, 256, 0, stream>>>(
            xb, xe, ye, ltm, cand, qidx, vid);
    } else {
        n3_fallback_kernel<<<NBX * NBY, 256, 0, stream>>>(
            x, xe, ye, ltm, cand, qidx, vid);
    }
    wvid_kernel<<<(QN + 255) / 256, 256, 0, stream>>>(wvid);
}

// Round 8
// 992.793 us; speedup vs baseline: 1.9515x; 1.9515x over previous
//
#include <hip/hip_runtime.h>
#include <hip/hip_bf16.h>
#include <math.h>

namespace {
constexpr int KNB  = 7;                  // neighbor volumes
constexpr int PS   = 7;                  // patch size
constexpr int CCH  = 3;                  // image channels
constexpr int IH   = 256;
constexpr int IW   = 256;
constexpr int PADR = 3;                  // PS/2
constexpr int QN   = IH * IW;            // 65536
constexpr int ON   = 32;                 // candidates per query
constexpr int EN   = 64;                 // embedding dim
constexpr int FN   = CCH * PS * PS;      // 147
constexpr int KC   = KNB * CCH;          // 21 output channels per map
constexpr int TQY  = 8;                  // tile rows
constexpr int TQX  = 4;                  // tile cols (= waves per block)
constexpr int CHY  = TQY + PS - 1;       // 14
constexpr int CHX  = TQX + PS - 1;       // 10
constexpr int CELEM = KC * CHY * CHX;    // 2940 canvas floats
constexpr int NW   = 4;                  // waves per block
constexpr int NBX  = IW / TQX;           // 64
constexpr int NBY  = IH / TQY;           // 32
constexpr int RP   = 192;                // padded row elems (bf16): 384 B = 3 lines
constexpr int RPB  = RP * 2;             // 384 bytes, 128B-aligned rows
constexpr int QR   = 8;                  // rows per quarter (32/4)
}

__device__ __forceinline__ float bf16_to_f(unsigned short u) {
    union { unsigned int i; float f; } c;
    c.i = ((unsigned int)u) << 16;
    return c.f;
}

// x fp32 [N][147] -> bf16 [N][192] (384B rows, zero-padded tail)
__global__ __launch_bounds__(256) void conv192_kernel(
    const float* __restrict__ x, unsigned short* __restrict__ xb)
{
    int t = blockIdx.x * blockDim.x + threadIdx.x;     // one per 8 out elems
    const int total = QN * (RP / 8);                   // 65536*24
    if (t >= total) return;
    int row = t / (RP / 8);
    int c8  = (t - row * (RP / 8)) * 8;
    const float* src = x + (size_t)row * FN;
    union { unsigned short u[8]; uint4 q; } v;
    #pragma unroll
    for (int j = 0; j < 8; ++j) {
        int e = c8 + j;
        float f = (e < FN) ? src[e] : 0.f;
        v.u[j] = __hip_bfloat16_raw(__float2bfloat16(f)).x;
    }
    *(uint4*)((char*)xb + (size_t)row * RPB + c8 * 2) = v.q;
}

// One block = 8x4 query tile, 4 waves; wave = one tile column, 8 queries
// serially. wpsum gather: whole 384B rows via dwordx4 (3 wave-loads per
// 8-row quarter), bounced through a wave-private LDS stage; quarter n+1's
// loads are issued while quarter n is FMA'd from LDS (software pipeline,
// single stage buffer, wave-private so no barriers).
// NOTE: (256,3) NOT (256,4): the (256,4) heuristic pins VGPR=64 and spills
// (rounds 3/4/7: ~1-3.6GB scratch). (256,3) allowed 84 VGPR in round 6.
__global__ __launch_bounds__(256, 3) void n3_tile_kernel(
    const unsigned short* __restrict__ xb,  // [N][192] bf16, 384B rows
    const float* __restrict__ xe,           // [N, E]
    const float* __restrict__ ye,           // [Q, E]
    const float* __restrict__ log_temp,     // [H, W]
    const int*   __restrict__ cand,         // [Q, O]
    const int*   __restrict__ qindex,       // [Q]
    float*       __restrict__ vid)          // [KC, H, W] (pre-zeroed)
{
    __shared__ float canvas[CELEM];                       // 11760 B
    __shared__ float w_lds[NW][ON][8];                    // 4096 B
    __shared__ int   off_lds[NW][ON];                     // 512 B (byte offs)
    __shared__ __align__(16) unsigned short xstage[NW][QR * RP]; // 12288 B

    const int wib  = threadIdx.x >> 6;  // 0..3 = tile column
    const int lane = threadIdx.x & 63;
    const int by   = blockIdx.x / NBX;
    const int bx   = blockIdx.x - by * NBX;
    const int y0   = by * TQY;
    const int x0   = bx * TQX;

    for (int i = threadIdx.x; i < CELEM; i += 256) canvas[i] = 0.f;
    __syncthreads();

    for (int ty = 0; ty < TQY; ++ty) {
        const int q = (y0 + ty) * IW + (x0 + wib);

        const int qpix = qindex[q];
        const int qi = qpix / IW;
        const int qj = qpix - qi * IW;

        // ---- lt: mean over zero-padded 7x7 log_temp patch ----
        float ltv = 0.f;
        if (lane < PS * PS) {
            int pi = lane / PS, pj = lane % PS;
            int yy = qi + pi - PADR, xx = qj + pj - PADR;
            if (yy >= 0 && yy < IH && xx >= 0 && xx < IW)
                ltv = log_temp[yy * IW + xx];
        }
        #pragma unroll
        for (int s = 32; s >= 1; s >>= 1) ltv += __shfl_xor(ltv, s);
        const float itemp = expf(-ltv * (1.f / 49.f));   // 1/exp(lt)

        // ---- search: lane = o + 32*h; each half-wave does half of E ----
        const int o = lane & 31;
        const int h = lane >> 5;
        const int cidx = cand[q * ON + o];
        if (lane < ON) off_lds[wib][o] = cidx * RPB;
        {
            const float4* xr = (const float4*)(xe + (size_t)cidx * EN) + h * 8;
            const float4* yr = (const float4*)(ye + (size_t)q * EN) + h * 8;
            float dot = 0.f, xn = 0.f, yn = 0.f;
            #pragma unroll
            for (int e = 0; e < 8; ++e) {
                float4 a = xr[e];
                float4 b = yr[e];
                dot += a.x * b.x + a.y * b.y + a.z * b.z + a.w * b.w;
                xn  += a.x * a.x + a.y * a.y + a.z * a.z + a.w * a.w;
                yn  += b.x * b.x + b.y * b.y + b.z * b.z + b.w * b.w;
            }
            float part = xn + yn - 2.f * dot;
            part += __shfl_xor(part, 32);    // both halves hold full d2
            // ---- NNN weights: 7 iterated softmaxes over 32-lane groups ----
            float logit = -part * itemp;
            float wk[KNB];
            #pragma unroll
            for (int k = 0; k < KNB; ++k) {
                float m = logit;
                #pragma unroll
                for (int s = 16; s >= 1; s >>= 1) m = fmaxf(m, __shfl_xor(m, s));
                float ev = expf(logit - m);
                float ssum = ev;
                #pragma unroll
                for (int s = 16; s >= 1; s >>= 1) ssum += __shfl_xor(ssum, s);
                float w = ev / ssum;
                wk[k] = w;
                logit += logf(fmaxf(1.f - w, 1e-6f));
            }
            if (lane < ON) {
                #pragma unroll
                for (int k = 0; k < KNB; ++k) w_lds[wib][lane][k] = wk[k];
            }
        }
        // wave-private LDS buffers: no __syncthreads needed

        // ---- wpsum: 4 quarters of 8 rows; row-gather via dwordx4 ----
        // slot = i*64+lane in [0,192): row = slot/24, 16B chunk = slot%24
        float acc[3][KNB];
        #pragma unroll
        for (int it = 0; it < 3; ++it)
            #pragma unroll
            for (int k = 0; k < KNB; ++k) acc[it][k] = 0.f;

        const int r0   = lane / 24;          // i=0 slot mapping
        const int s0   = lane - r0 * 24;
        const int r1   = (64 + lane) / 24;
        const int s1   = (64 + lane) - r1 * 24;
        const int r2   = (128 + lane) / 24;
        const int s2   = (128 + lane) - r2 * 24;

        uint4 g0, g1, g2;
        {   // prologue: issue quarter 0
            const int* offq = &off_lds[wib][0];
            g0 = *(const uint4*)((const char*)xb + offq[r0] + s0 * 16);
            g1 = *(const uint4*)((const char*)xb + offq[r1] + s1 * 16);
            g2 = *(const uint4*)((const char*)xb + offq[r2] + s2 * 16);
        }

        char* const xsb = (char*)&xstage[wib][0];

        #pragma unroll
        for (int qt = 0; qt < 4; ++qt) {
            // write current quarter to stage (waits on its vmcnt only)
            *(uint4*)(xsb + (lane)        * 16) = g0;
            *(uint4*)(xsb + (64 + lane)   * 16) = g1;
            *(uint4*)(xsb + (128 + lane)  * 16) = g2;
            // issue next quarter's loads (in flight during FMA below)
            if (qt < 3) {
                const int* offq = &off_lds[wib][(qt + 1) * QR];
                g0 = *(const uint4*)((const char*)xb + offq[r0] + s0 * 16);
                g1 = *(const uint4*)((const char*)xb + offq[r1] + s1 * 16);
                g2 = *(const uint4*)((const char*)xb + offq[r2] + s2 * 16);
            }
            // FMA current quarter from LDS (lgkm ordering by compiler)
            const unsigned short* xs = &xstage[wib][0];
            #pragma unroll
            for (int r = 0; r < QR; ++r) {
                const int oo = qt * QR + r;
                const float4 wa = *(const float4*)&w_lds[wib][oo][0];
                const float4 wb = *(const float4*)&w_lds[wib][oo][4];
                #pragma unroll
                for (int it = 0; it < 3; ++it) {
                    const float xv = bf16_to_f(xs[r * RP + it * 64 + lane]);
                    acc[it][0] += xv * wa.x;
                    acc[it][1] += xv * wa.y;
                    acc[it][2] += xv * wa.z;
                    acc[it][3] += xv * wa.w;
                    acc[it][4] += xv * wb.x;
                    acc[it][5] += xv * wb.y;
                    acc[it][6] += xv * wb.z;
                }
            }
        }

        // ---- fold into LDS canvas ----
        #pragma unroll
        for (int it = 0; it < 3; ++it) {
            const int f = it * 64 + lane;
            if (f < FN) {
                const int c  = f / (PS * PS);
                const int r  = f - c * (PS * PS);
                const int pi = r / PS;
                const int pj = r - pi * PS;
                const int ly = qi + pi - y0;
                const int lx = qj + pj - x0;
                #pragma unroll
                for (int k = 0; k < KNB; ++k)
                    atomicAdd(&canvas[(k * CCH + c) * (CHY * CHX) + ly * CHX + lx],
                              acc[it][k]);
            }
        }
    }

    __syncthreads();

    // ---- flush canvas to global with crop bounds-check ----
    for (int i = threadIdx.x; i < CELEM; i += 256) {
        const float v = canvas[i];
        if (v != 0.f) {
            const int ch  = i / (CHY * CHX);
            const int rem = i - ch * (CHY * CHX);
            const int ly  = rem / CHX;
            const int lx  = rem - ly * CHX;
            const int gy  = y0 - PADR + ly;
            const int gx  = x0 - PADR + lx;
            if (gy >= 0 && gy < IH && gx >= 0 && gx < IW)
                atomicAdd(&vid[(size_t)ch * QN + gy * IW + gx], v);
        }
    }
}

// Fallback (ws too small): round-2-verified structure, fp32 x gather.
__global__ __launch_bounds__(256, 4) void n3_fallback_kernel(
    const float* __restrict__ x,
    const float* __restrict__ xe,
    const float* __restrict__ ye,
    const float* __restrict__ log_temp,
    const int*   __restrict__ cand,
    const int*   __restrict__ qindex,
    float*       __restrict__ vid)
{
    __shared__ float canvas[CELEM];
    __shared__ float w_lds[NW][ON][8];
    __shared__ int   off_lds[NW][ON];

    const int wib  = threadIdx.x >> 6;
    const int lane = threadIdx.x & 63;
    const int by   = blockIdx.x / NBX;
    const int bx   = blockIdx.x - by * NBX;
    const int y0   = by * TQY;
    const int x0   = bx * TQX;

    for (int i = threadIdx.x; i < CELEM; i += 256) canvas[i] = 0.f;
    __syncthreads();

    for (int ty = 0; ty < TQY; ++ty) {
        const int q = (y0 + ty) * IW + (x0 + wib);
        const int qpix = qindex[q];
        const int qi = qpix / IW;
        const int qj = qpix - qi * IW;

        float ltv = 0.f;
        if (lane < PS * PS) {
            int pi = lane / PS, pj = lane % PS;
            int yy = qi + pi - PADR, xx = qj + pj - PADR;
            if (yy >= 0 && yy < IH && xx >= 0 && xx < IW)
                ltv = log_temp[yy * IW + xx];
        }
        #pragma unroll
        for (int s = 32; s >= 1; s >>= 1) ltv += __shfl_xor(ltv, s);
        const float itemp = expf(-ltv * (1.f / 49.f));

        const int o = lane & 31;
        const int h = lane >> 5;
        const int cidx = cand[q * ON + o];
        if (lane < ON) off_lds[wib][o] = cidx * FN;
        {
            const float4* xr = (const float4*)(xe + (size_t)cidx * EN) + h * 8;
            const float4* yr = (const float4*)(ye + (size_t)q * EN) + h * 8;
            float dot = 0.f, xn = 0.f, yn = 0.f;
            #pragma unroll
            for (int e = 0; e < 8; ++e) {
                float4 a = xr[e];
                float4 b = yr[e];
                dot += a.x * b.x + a.y * b.y + a.z * b.z + a.w * b.w;
                xn  += a.x * a.x + a.y * a.y + a.z * a.z + a.w * a.w;
                yn  += b.x * b.x + b.y * b.y + b.z * b.z + b.w * b.w;
            }
            float part = xn + yn - 2.f * dot;
            part += __shfl_xor(part, 32);
            float logit = -part * itemp;
            float wk[KNB];
            #pragma unroll
            for (int k = 0; k < KNB; ++k) {
                float m = logit;
                #pragma unroll
                for (int s = 16; s >= 1; s >>= 1) m = fmaxf(m, __shfl_xor(m, s));
                float ev = expf(logit - m);
                float ssum = ev;
                #pragma unroll
                for (int s = 16; s >= 1; s >>= 1) ssum += __shfl_xor(ssum, s);
                float w = ev / ssum;
                wk[k] = w;
                logit += logf(fmaxf(1.f - w, 1e-6f));
            }
            if (lane < ON) {
                #pragma unroll
                for (int k = 0; k < KNB; ++k) w_lds[wib][lane][k] = wk[k];
            }
        }

        #pragma unroll
        for (int it = 0; it < 3; ++it) {
            const int f = it * 64 + lane;
            const bool act = f < FN;
            float acc[KNB];
            #pragma unroll
            for (int k = 0; k < KNB; ++k) acc[k] = 0.f;
            #pragma unroll 8
            for (int oo = 0; oo < ON; ++oo) {
                const int off = off_lds[wib][oo];
                const float xv = act ? x[off + f] : 0.f;
                #pragma unroll
                for (int k = 0; k < KNB; ++k) acc[k] += xv * w_lds[wib][oo][k];
            }
            if (act) {
                const int c  = f / (PS * PS);
                const int r  = f - c * (PS * PS);
                const int pi = r / PS;
                const int pj = r - pi * PS;
                const int ly = qi + pi - y0;
                const int lx = qj + pj - x0;
                #pragma unroll
                for (int k = 0; k < KNB; ++k)
                    atomicAdd(&canvas[(k * CCH + c) * (CHY * CHX) + ly * CHX + lx], acc[k]);
            }
        }
    }

    __syncthreads();

    for (int i = threadIdx.x; i < CELEM; i += 256) {
        const float v = canvas[i];
        if (v != 0.f) {
            const int ch  = i / (CHY * CHX);
            const int rem = i - ch * (CHY * CHX);
            const int ly  = rem / CHX;
            const int lx  = rem - ly * CHX;
            const int gy  = y0 - PADR + ly;
            const int gx  = x0 - PADR + lx;
            if (gy >= 0 && gy < IH && gx >= 0 && gx < IW)
                atomicAdd(&vid[(size_t)ch * QN + gy * IW + gx], v);
        }
    }
}

// wvid = fold(ones) with qindex = arange(H*W): separable border counts.
__global__ __launch_bounds__(256) void wvid_kernel(float* __restrict__ wvid) {
    int idx = blockIdx.x * blockDim.x + threadIdx.x;
    if (idx >= QN) return;
    int y  = idx / IW;
    int xx = idx - y * IW;
    int cy = min(PS - 1, y  + PADR) - max(0, y  - (IH - 1 - PADR)) + 1;
    int cx = min(PS - 1, xx + PADR) - max(0, xx - (IW - 1 - PADR)) + 1;
    float v = (float)(cy * cx);
    #pragma unroll
    for (int ch = 0; ch < KC; ++ch) wvid[(size_t)ch * QN + idx] = v;
}

extern "C" void kernel_launch(void* const* d_in, const int* in_sizes, int n_in,
                              void* d_out, int out_size, void* d_ws, size_t ws_size,
                              hipStream_t stream) {
    const float* x    = (const float*)d_in[0];
    const float* xe   = (const float*)d_in[1];
    const float* ye   = (const float*)d_in[2];
    const float* ltm  = (const float*)d_in[3];
    const int*   cand = (const int*)d_in[4];
    const int*   qidx = (const int*)d_in[5];

    float* vid  = (float*)d_out;
    float* wvid = vid + (size_t)KC * QN;

    // vid is accumulated with atomics -> must be zeroed every launch
    hipMemsetAsync(vid, 0, (size_t)KC * QN * sizeof(float), stream);

    const size_t xbytes = (size_t)QN * RPB;   // 25.2 MB

    if (ws_size >= xbytes) {
        unsigned short* xb = (unsigned short*)d_ws;
        const int nconv = QN * (RP / 8);
        conv192_kernel<<<(nconv + 255) / 256, 256, 0, stream>>>(x, xb);
        n3_tile_kernel<<<NBX * NBY, 256, 0, stream>>>(
            xb, xe, ye, ltm, cand, qidx, vid);
    } else {
        n3_fallback_kernel<<<NBX * NBY, 256, 0, stream>>>(
            x, xe, ye, ltm, cand, qidx, vid);
    }
    wvid_kernel<<<(QN + 255) / 256, 256, 0, stream>>>(wvid);
}